// Round 15
// baseline (83.117 us; speedup 1.0000x reference)
//
#include <hip/hip_runtime.h>
#include <hip/hip_bf16.h>

typedef short short8 __attribute__((ext_vector_type(8)));
typedef short short4v __attribute__((ext_vector_type(4)));
typedef float f32x4 __attribute__((ext_vector_type(4)));
typedef unsigned int uint2v __attribute__((ext_vector_type(2)));

#define NPTS 4096
#define BATCH 8
#define PTOT 32768
#define FEATS 128
#define KK 20
#define OUTC 64
#define PTS_PER_WAVE 8
#define WAVES 4

__device__ __forceinline__ unsigned short f2bf(float f){
  union { __hip_bfloat16 h; unsigned short u; } v;
  v.h = __hip_bfloat16(f);
  return v.u;
}

__device__ __forceinline__ void gload_lds16(const void* src, void* dst){
  __builtin_amdgcn_global_load_lds((const __attribute__((address_space(1))) void*)src,
                                   (__attribute__((address_space(3))) void*)dst, 16, 0, 0);
}

// feature [B,128,N] f32 -> flat [B*N, 128] bf16
__global__ void k_transpose(const float* __restrict__ f, unsigned short* __restrict__ flat){
  __shared__ float tile[32][33];
  int b = blockIdx.z, c0 = blockIdx.y*32, n0 = blockIdx.x*32;
  int tx = threadIdx.x, ty = threadIdx.y;   // (32,8)
  const float* src = f + ((size_t)b*FEATS + c0)*NPTS + n0;
  #pragma unroll
  for(int i=0;i<4;i++) tile[ty+8*i][tx] = src[(size_t)(ty+8*i)*NPTS + tx];
  __syncthreads();
  unsigned short* dst = flat + ((size_t)b*NPTS + n0)*FEATS + c0;
  #pragma unroll
  for(int i=0;i<4;i++) dst[(size_t)(ty+8*i)*FEATS + tx] = f2bf(tile[tx][ty+8*i]);
}

// conv_w f32 [64][128] -> bf16 fragment table: e = (((ks*4+n2)*4+lg)*16+l15)*8+j
__global__ void k_wpack(const float* __restrict__ convw, unsigned short* __restrict__ wp){
  int e = blockIdx.x*256 + threadIdx.x;    // 8192 total
  int j = e & 7, l15 = (e>>3)&15, lg = (e>>7)&3, n2 = (e>>9)&3, ks = e>>11;
  int o = n2*16 + l15, c = ks*32 + lg*8 + j;
  wp[e] = f2bf(convw[o*FEATS + c]);
}

// Laws: (256,3) relaxed cap ((256,4)->64 VGPR->spill, r7). Perm register-
// prefetch across MFMAs spills (r8) -> perm via LDS DMA. pbuf DOUBLE +
// counted vmcnt, never drain 0 in loop (r10 vs r11). Batched stores + idx in
// LDS (r12). W in LDS so GEMM2 issues zero VMEM and the counted pipeline
// holds (r14: 74.6->68). NEW r15: merge gather/GEMM1-output buffers
// (r6-proven aliasing) + 2-slot ybuf -> LDS 54,272 B -> 3 blocks/CU with the
// r14 pipeline intact. Both STAGEs move post-GEMM2 in G-then-P order so the
// vmcnt(2) queue math still holds (G older than next P).
__global__ __launch_bounds__(256, 3) void k_main(
    const unsigned short* __restrict__ flat,
    const float* __restrict__ perm_g,
    const unsigned short* __restrict__ wpack,
    const int*   __restrict__ idx_g,
    float* __restrict__ out,
    float* __restrict__ stats)
{
  const int t = threadIdx.x, lane = t & 63, w = t >> 6;
  const int l15 = lane & 15, lg = lane >> 4;

  //  buf: gather subtiles [cgrp 0..7][kgrp 0..4][4][16] u16 (DMA target),
  //       then overwritten in-place by GEMM1 output (.view layout, swizzled).
  //       Safe: tr-reads hard-complete (lgkmcnt(0)) before GEMM1 writes;
  //       STAGE_G(pi+1) issues post-GEMM2, its DMA lands >=500cy later, long
  //       after GEMM2's in-order DS reads retired (r6/r7/r8-proven).
  //  pbuf: perm f32 DOUBLE buffer, DMA'd two iterations ahead
  //  W_lds: conv_w fragment table (block-shared, read-only after barrier)
  __shared__ __align__(16) unsigned short buf_all[WAVES][2560];     // 20480 B
  __shared__ __align__(16) float pbuf_all[WAVES][2][400];           // 12800 B
  __shared__ __align__(16) unsigned short W_lds[8192];              // 16384 B
  __shared__ int   idx_all[WAVES][160];                             // 2560 B (red aliases after)
  __shared__ float ybuf_all[WAVES][2*OUTC];                         // 2048 B
  // total 54,272 B <= 163,840/3 -> 3 blocks/CU

  unsigned short* buf = buf_all[w];
  int*   idxb = idx_all[w];
  float* ybuf = ybuf_all[w];
  const unsigned bufb = (unsigned)(size_t)(const __attribute__((address_space(3))) void*)buf;

  const int p0 = blockIdx.x*(WAVES*PTS_PER_WAVE) + w*PTS_PER_WAVE;

  // ---- idx prefetch: 160 ints for this wave's 8 points (coalesced) ----
  {
    const int* ib = idx_g + (size_t)p0*KK;
    idxb[lane]      = ib[lane];
    idxb[64+lane]   = ib[64+lane];
    if(lane < 32) idxb[128+lane] = ib[128+lane];
  }

  // ---- W table: 16 KB global -> LDS via DMA (lane-linear, layout preserved) ----
  #pragma unroll
  for(int it=0; it<4; it++){
    gload_lds16((const char*)wpack + it*4096 + (size_t)t*16,
                (char*)W_lds + it*4096 + w*1024);
  }
  asm volatile("s_waitcnt vmcnt(0)" ::: "memory");   // drains only W DMAs
  __syncthreads();                                    // one-time barrier

  // ---- per-lane staging map: chunk q = it*64+lane -> (cgrp,kgrp,krem,chalf) ----
  int krowb4[5], colb[5];
  #pragma unroll
  for(int it=0; it<5; it++){
    int q = it*64 + lane;
    int cg = q/40, r = q - cg*40;
    int kgr = r>>3, rem = r&7, krem = rem>>1, chalf = rem&1;
    krowb4[it] = (kgr*4 + krem)*4;      // idx byte offset for row k
    colb[it]   = cg*32 + chalf*16;      // byte offset within flat row
  }

  // ---- tr-read addresses: cross-lane group-transpose semantics ----
  int kg0 = 2*lg;   if(kg0 > 4) kg0 = 0;
  int kg1 = 2*lg+1; if(kg1 > 4) kg1 = 0;
  const unsigned tra0 = bufb + kg0*128 + l15*8;
  const unsigned tra1 = bufb + kg1*128 + l15*8;

  // ---- perm offsets into pbuf (clamped in-bounds; A zeroed for k>=20) ----
  const int s2 = (l15 < 4) ? (16 + l15) : 19;
  int koff[8];
  #pragma unroll
  for(int j=0;j<8;j++){ int kb = lg*160 + j*20; koff[j] = (kb > 380) ? 380 : kb; }

  float bsum[4] = {0,0,0,0}, bsq[4] = {0,0,0,0};

  #define STAGE_G(PI) do{                                                       \
    int pib_ = (PI)*80;                                                         \
    _Pragma("unroll")                                                           \
    for(int it_=0; it_<5; it_++){                                               \
      int id_ = *(const int*)((const char*)idxb + pib_ + krowb4[it_]);          \
      const char* s_ = (const char*)flat + ((size_t)(unsigned)id_*256) + colb[it_]; \
      gload_lds16(s_, (char*)buf + it_*1024);                                   \
    } }while(0)

  #define STAGE_P(PI) do{                                                       \
    const char* ps_ = (const char*)(perm_g + (size_t)(p0+(PI))*400);            \
    char* pd_ = (char*)&pbuf_all[w][(PI)&1][0];                                 \
    gload_lds16(ps_ + (size_t)lane*16, pd_);                                    \
    gload_lds16(ps_ + 576 + (size_t)lane*16, pd_ + 576);                        \
  }while(0)

  // prologue in-flight: [G(0) x5, P(0) x2, P(1) x2] (G oldest)
  STAGE_G(0); STAGE_P(0); STAGE_P(1);

  const int bb = p0 >> 12, nn0 = p0 & (NPTS-1);

  for(int pi=0; pi<PTS_PER_WAVE; pi++){
    // ---- counted wait. Steady queue at top: [P(pi)2, (S)1, G(pi)5, P(pi+1)2]
    //      -> vmcnt(2) drains P(pi)+S+G(pi), keeps P(pi+1) in flight ----
    if(pi == PTS_PER_WAVE-1) asm volatile("s_waitcnt vmcnt(0)" ::: "memory");
    else                     asm volatile("s_waitcnt vmcnt(2)" ::: "memory");

    // ---- flush point-pair (pi-2, pi-1) at pi = 2,4,6 (batched float2) ----
    if(pi >= 2 && (pi & 1) == 0){
      float* op = out + ((size_t)bb*OUTC + lane)*NPTS + nn0 + (pi-2);
      float2 v;
      v.x = ybuf[lane];        // slot 0 = even point pi-2
      v.y = ybuf[64 + lane];   // slot 1 = odd  point pi-1
      *(float2*)op = v;
    }

    // ---- 16 transpose-reads from buf + 16 pack reads from pbuf[pi&1] ----
    short4v lo[8], hi[8];
    #pragma unroll
    for(int nt=0; nt<8; nt++){
      asm volatile("ds_read_b64_tr_b16 %0, %1 offset:%2" : "=v"(lo[nt]) : "v"(tra0), "i"(nt*640));
      asm volatile("ds_read_b64_tr_b16 %0, %1 offset:%2" : "=v"(hi[nt]) : "v"(tra1), "i"(nt*640));
    }
    const float* pb = &pbuf_all[w][pi&1][0];
    float p0r[8], p1r[8];
    #pragma unroll
    for(int j=0;j<8;j++){ p0r[j] = pb[koff[j]+l15]; p1r[j] = pb[koff[j]+s2]; }

    asm volatile("s_waitcnt lgkmcnt(0)" ::: "memory");
    __builtin_amdgcn_sched_barrier(0);                 // rule #18: pin consumers after the wait

    // ---- pack perm A-frags (pure VALU on LDS-read values) ----
    short8 a0f, a1f;
    #pragma unroll
    for(int j=0;j<8;j++){
      int kk2 = lg*8 + j;
      a0f[j] = (kk2 < KK) ? (short)f2bf(p0r[j]) : (short)0;
      a1f[j] = (kk2 < KK) ? (short)f2bf(p1r[j]) : (short)0;
    }

    // ---- GEMM1: D[s][c] = sum_k perm[k][s]*gath[k][c]; overwrite buf (.view) ----
    #pragma unroll
    for(int nt=0; nt<8; nt++){
      short8 gf = __builtin_shufflevector(lo[nt], hi[nt], 0,1,2,3,4,5,6,7);
      f32x4 z = {0.f,0.f,0.f,0.f};
      f32x4 c0 = __builtin_amdgcn_mfma_f32_16x16x32_bf16(a0f, gf, z, 0,0,0);
      f32x4 c1 = __builtin_amdgcn_mfma_f32_16x16x32_bf16(a1f, gf, z, 0,0,0);
      const int c = nt*16 + l15;
      {
        int f0 = c*20 + lg*4;                          // s = 4*lg + r
        int byt = (f0*2) ^ (((f0>>7)&7)<<4);
        uint2v pk;
        pk.x = (unsigned)f2bf(c0[0]) | ((unsigned)f2bf(c0[1])<<16);
        pk.y = (unsigned)f2bf(c0[2]) | ((unsigned)f2bf(c0[3])<<16);
        *(uint2v*)((char*)buf + byt) = pk;
      }
      if(lg == 0){
        int f0 = c*20 + 16;                            // s = 16 + r
        int byt = (f0*2) ^ (((f0>>7)&7)<<4);
        uint2v pk;
        pk.x = (unsigned)f2bf(c1[0]) | ((unsigned)f2bf(c1[1])<<16);
        pk.y = (unsigned)f2bf(c1[2]) | ((unsigned)f2bf(c1[3])<<16);
        *(uint2v*)((char*)buf + byt) = pk;
      }
    }

    // ---- GEMM2: D[kp][o] = sum_c' T[kp][c'] * W[o][c'] — W from LDS, zero VMEM ----
    f32x4 acc[2][4];
    #pragma unroll
    for(int m2=0;m2<2;m2++)
      #pragma unroll
      for(int n2=0;n2<4;n2++){ f32x4 z={0.f,0.f,0.f,0.f}; acc[m2][n2]=z; }

    const int kp1 = (l15 < 4) ? (16 + l15) : 19;       // clamped; dup rows masked in epilogue
    #pragma unroll
    for(int ks=0; ks<4; ks++){
      int a0b = (l15*256 + ks*64 + lg*16) ^ ((l15&7)<<4);
      int a1b = (kp1*256 + ks*64 + lg*16) ^ ((kp1&7)<<4);
      short8 t0 = *(const short8*)((const char*)buf + a0b);
      short8 t1 = *(const short8*)((const char*)buf + a1b);
      #pragma unroll
      for(int n2=0; n2<4; n2++){
        short8 wf = *(const short8*)((const char*)W_lds + (ks*4+n2)*1024 + lane*16);
        acc[0][n2] = __builtin_amdgcn_mfma_f32_16x16x32_bf16(t0, wf, acc[0][n2], 0,0,0);
        acc[1][n2] = __builtin_amdgcn_mfma_f32_16x16x32_bf16(t1, wf, acc[1][n2], 0,0,0);
      }
    }

    // ---- prefetch AFTER GEMM2 (merged-buffer safety), order G then P
    //      so next iteration's vmcnt(2) leaves only P(pi+2) in flight ----
    if(pi+1 < PTS_PER_WAVE) STAGE_G(pi+1);
    if(pi+2 < PTS_PER_WAVE) STAGE_P(pi+2);

    // ---- epilogue: max over kp -> ybuf slot (pi&1), BN partials ----
    #pragma unroll
    for(int n2=0; n2<4; n2++){
      float m0 = fmaxf(fmaxf(acc[0][n2][0], acc[0][n2][1]),
                       fmaxf(acc[0][n2][2], acc[0][n2][3]));
      float m1 = fmaxf(fmaxf(acc[1][n2][0], acc[1][n2][1]),
                       fmaxf(acc[1][n2][2], acc[1][n2][3]));
      float mm = fmaxf(m0, (lg == 0) ? m1 : -3.4e38f);
      mm = fmaxf(mm, __shfl_xor(mm, 16));
      mm = fmaxf(mm, __shfl_xor(mm, 32));
      if(lg == 0) ybuf[(pi&1)*64 + n2*16 + l15] = mm;  // conv bias cancels under BN
      bsum[n2] += mm; bsq[n2] += mm*mm;
    }
  }

  // ---- final flush: points 6,7 ----
  {
    float* op = out + ((size_t)bb*OUTC + lane)*NPTS + nn0 + 6;
    float2 v;
    v.x = ybuf[lane];        // slot 0 = point 6
    v.y = ybuf[64 + lane];   // slot 1 = point 7
    *(float2*)op = v;
  }

  // ---- block-level stats reduction (red aliases idx storage) ----
  float* red = (float*)&idx_all[0][0];
  __syncthreads();
  if(lg == 0){
    #pragma unroll
    for(int n2=0; n2<4; n2++){
      int o = n2*16 + l15;
      red[w*128 + o]      = bsum[n2];
      red[w*128 + 64 + o] = bsq[n2];
    }
  }
  __syncthreads();
  if(w == 0){
    float s = red[lane] + red[128+lane] + red[256+lane] + red[384+lane];
    atomicAdd(&stats[lane], s);
  } else if(w == 1){
    float s = red[64+lane] + red[192+lane] + red[320+lane] + red[448+lane];
    atomicAdd(&stats[64+lane], s);
  }
}

// fused finalize + apply
__global__ void k_bn2(float* __restrict__ out, const float* __restrict__ stats,
                      const float* __restrict__ gamma, const float* __restrict__ beta){
  __shared__ float ss[128];
  int t = threadIdx.x;
  if(t < 64){
    float inv = 1.f/(float)PTOT;
    float mean = stats[t]*inv;
    float var  = stats[64+t]*inv - mean*mean;
    float rstd = rsqrtf(var + 1e-5f);
    float sc = gamma[t]*rstd;
    ss[t]    = sc;
    ss[64+t] = beta[t] - mean*sc;
  }
  __syncthreads();
  int i = blockIdx.x*256 + t;               // over float4s
  float4 v = ((float4*)out)[i];
  int o = (i >> 10) & 63;
  float sc = ss[o], sh = ss[64+o];
  v.x = v.x*sc + sh; v.y = v.y*sc + sh; v.z = v.z*sc + sh; v.w = v.w*sc + sh;
  ((float4*)out)[i] = v;
}

extern "C" void kernel_launch(void* const* d_in, const int* in_sizes, int n_in,
                              void* d_out, int out_size, void* d_ws, size_t ws_size,
                              hipStream_t stream){
  (void)in_sizes; (void)n_in; (void)ws_size;
  const float* feature    = (const float*)d_in[0];
  const float* permatrix  = (const float*)d_in[1];
  const float* conv_w     = (const float*)d_in[2];
  // d_in[3] = conv_b: cancelled exactly by training-mode BatchNorm
  const float* bn_gamma   = (const float*)d_in[4];
  const float* bn_beta    = (const float*)d_in[5];
  const int*   sp_idx     = (const int*)d_in[6];
  float* out = (float*)d_out;

  unsigned short* flat  = (unsigned short*)d_ws;                         // 8 MB
  float* stats          = (float*)((char*)d_ws + (size_t)8*1024*1024);   // 128 f32
  unsigned short* wpack = (unsigned short*)((char*)d_ws + (size_t)8*1024*1024 + 4096); // 16 KB

  hipMemsetAsync(stats, 0, 128*sizeof(float), stream);

  dim3 gT(NPTS/32, FEATS/32, BATCH), bT(32,8);
  k_transpose<<<gT, bT, 0, stream>>>(feature, flat);
  k_wpack<<<dim3(32), dim3(256), 0, stream>>>(conv_w, wpack);

  k_main<<<dim3(PTOT/(WAVES*PTS_PER_WAVE)), dim3(256), 0, stream>>>(
      flat, permatrix, wpack, sp_idx, out, stats);

  k_bn2<<<dim3(out_size/4/256), dim3(256), 0, stream>>>(out, stats, bn_gamma, bn_beta);
}

// Round 16
// 77.091 us; speedup vs baseline: 1.0782x; 1.0782x over previous
//
#include <hip/hip_runtime.h>
#include <hip/hip_bf16.h>

typedef short short8 __attribute__((ext_vector_type(8)));
typedef short short4v __attribute__((ext_vector_type(4)));
typedef float f32x4 __attribute__((ext_vector_type(4)));
typedef unsigned int uint2v __attribute__((ext_vector_type(2)));

#define NPTS 4096
#define BATCH 8
#define PTOT 32768
#define FEATS 128
#define KK 20
#define OUTC 64
#define PTS_PER_WAVE 16
#define WAVES 4

__device__ __forceinline__ unsigned short f2bf(float f){
  union { __hip_bfloat16 h; unsigned short u; } v;
  v.h = __hip_bfloat16(f);
  return v.u;
}

__device__ __forceinline__ void gload_lds16(const void* src, void* dst){
  __builtin_amdgcn_global_load_lds((const __attribute__((address_space(1))) void*)src,
                                   (__attribute__((address_space(3))) void*)dst, 16, 0, 0);
}

// feature [B,128,N] f32 -> flat [B*N, 128] bf16; 32 blocks also pack conv_w
__global__ void k_transpose(const float* __restrict__ f, unsigned short* __restrict__ flat,
                            const float* __restrict__ convw, unsigned short* __restrict__ wp){
  __shared__ float tile[32][33];
  int b = blockIdx.z, c0 = blockIdx.y*32, n0 = blockIdx.x*32;
  int tx = threadIdx.x, ty = threadIdx.y;   // (32,8)
  const float* src = f + ((size_t)b*FEATS + c0)*NPTS + n0;
  #pragma unroll
  for(int i=0;i<4;i++) tile[ty+8*i][tx] = src[(size_t)(ty+8*i)*NPTS + tx];
  // fused wpack: e = (((ks*4+n2)*4+lg)*16+l15)*8+j  (32 blocks x 256 threads)
  if(blockIdx.z == 0 && blockIdx.y == 0 && blockIdx.x < 32){
    int e = blockIdx.x*256 + ty*32 + tx;
    int j = e & 7, l15 = (e>>3)&15, lg = (e>>7)&3, n2 = (e>>9)&3, ks = e>>11;
    int o = n2*16 + l15, c = ks*32 + lg*8 + j;
    wp[e] = f2bf(convw[o*FEATS + c]);
  }
  __syncthreads();
  unsigned short* dst = flat + ((size_t)b*NPTS + n0)*FEATS + c0;
  #pragma unroll
  for(int i=0;i<4;i++) dst[(size_t)(ty+8*i)*FEATS + tx] = f2bf(tile[tx][ty+8*i]);
}

// Laws: (256,3) relaxed cap ((256,4)->64 VGPR->spill, r7). Perm register-
// prefetch across MFMAs spills (r8) -> perm via LDS DMA. pbuf DOUBLE +
// counted vmcnt, never drain 0 in loop (r10 vs r11). Batched stores + idx in
// LDS (r12). W in LDS -> GEMM2 zero VMEM, pipeline holds (r14: 74.6->68).
// Occupancy pushes (r11/r12/r13/r15) all lost to per-wave stall cover: keep
// r14's split-buffer early-STAGE_G schedule. r16: 16 pts/wave (grid 512,
// exactly one 2-block/CU round, prologue amortized) + s_setprio around MFMA
// clusters (independent-wave regime, m191-style).
__global__ __launch_bounds__(256, 3) void k_main(
    const unsigned short* __restrict__ flat,
    const float* __restrict__ perm_g,
    const unsigned short* __restrict__ wpack,
    const int*   __restrict__ idx_g,
    float* __restrict__ out,
    float* __restrict__ stats)
{
  const int t = threadIdx.x, lane = t & 63, w = t >> 6;
  const int l15 = lane & 15, lg = lane >> 4;

  //  gbuf: gather dest [cgrp 0..7][kgrp 0..4][4][16] u16 (DMA, depth-1)
  //  tbuf: GEMM1 output, .view layout XOR-swizzled (split from gbuf so
  //        STAGE_G(pi+1) issues BEFORE GEMM1(pi) -> full GEMM1+GEMM2 cover)
  //  pbuf: perm f32 DOUBLE buffer, DMA'd two iterations ahead
  //  W_lds: conv_w fragment table (block-shared, read-only after barrier)
  __shared__ __align__(16) unsigned short gbuf_all[WAVES][2560];     // 20480 B
  __shared__ __align__(16) unsigned short tbuf_all[WAVES][2560];     // 20480 B
  __shared__ __align__(16) float pbuf_all[WAVES][2][400];            // 12800 B
  __shared__ __align__(16) unsigned short W_lds[8192];               // 16384 B
  __shared__ int   idx_all[WAVES][320];                              // 5120 B (red aliases after)
  __shared__ float ybuf_all[WAVES][4*OUTC];                          // 4096 B
  // total 79,360 B -> 2 blocks/CU

  unsigned short* gbuf = gbuf_all[w];
  unsigned short* tbuf = tbuf_all[w];
  int*   idxb = idx_all[w];
  float* ybuf = ybuf_all[w];
  const unsigned gbufb = (unsigned)(size_t)(const __attribute__((address_space(3))) void*)gbuf;

  const int p0 = blockIdx.x*(WAVES*PTS_PER_WAVE) + w*PTS_PER_WAVE;

  // ---- idx prefetch: 320 ints for this wave's 16 points (coalesced) ----
  {
    const int* ib = idx_g + (size_t)p0*KK;
    #pragma unroll
    for(int it=0; it<5; it++) idxb[it*64 + lane] = ib[it*64 + lane];
  }

  // ---- W table: 16 KB global -> LDS via DMA (lane-linear, layout preserved) ----
  #pragma unroll
  for(int it=0; it<4; it++){
    gload_lds16((const char*)wpack + it*4096 + (size_t)t*16,
                (char*)W_lds + it*4096 + w*1024);
  }
  asm volatile("s_waitcnt vmcnt(0)" ::: "memory");   // drains only W DMAs
  __syncthreads();                                    // one-time barrier

  // ---- per-lane staging map: chunk q = it*64+lane -> (cgrp,kgrp,krem,chalf) ----
  int krowb4[5], colb[5];
  #pragma unroll
  for(int it=0; it<5; it++){
    int q = it*64 + lane;
    int cg = q/40, r = q - cg*40;
    int kgr = r>>3, rem = r&7, krem = rem>>1, chalf = rem&1;
    krowb4[it] = (kgr*4 + krem)*4;      // idx byte offset for row k
    colb[it]   = cg*32 + chalf*16;      // byte offset within flat row
  }

  // ---- tr-read addresses: cross-lane group-transpose semantics ----
  int kg0 = 2*lg;   if(kg0 > 4) kg0 = 0;
  int kg1 = 2*lg+1; if(kg1 > 4) kg1 = 0;
  const unsigned tra0 = gbufb + kg0*128 + l15*8;
  const unsigned tra1 = gbufb + kg1*128 + l15*8;

  // ---- perm offsets into pbuf (clamped in-bounds; A zeroed for k>=20) ----
  const int s2 = (l15 < 4) ? (16 + l15) : 19;
  int koff[8];
  #pragma unroll
  for(int j=0;j<8;j++){ int kb = lg*160 + j*20; koff[j] = (kb > 380) ? 380 : kb; }

  float bsum[4] = {0,0,0,0}, bsq[4] = {0,0,0,0};

  #define STAGE_G(PI) do{                                                       \
    int pib_ = (PI)*80;                                                         \
    _Pragma("unroll")                                                           \
    for(int it_=0; it_<5; it_++){                                               \
      int id_ = *(const int*)((const char*)idxb + pib_ + krowb4[it_]);          \
      const char* s_ = (const char*)flat + ((size_t)(unsigned)id_*256) + colb[it_]; \
      gload_lds16(s_, (char*)gbuf + it_*1024);                                  \
    } }while(0)

  #define STAGE_P(PI) do{                                                       \
    const char* ps_ = (const char*)(perm_g + (size_t)(p0+(PI))*400);            \
    char* pd_ = (char*)&pbuf_all[w][(PI)&1][0];                                 \
    gload_lds16(ps_ + (size_t)lane*16, pd_);                                    \
    gload_lds16(ps_ + 576 + (size_t)lane*16, pd_ + 576);                        \
  }while(0)

  // prologue in-flight: [G(0) x5, P(0) x2, P(1) x2]
  STAGE_G(0); STAGE_P(0); STAGE_P(1);

  const int bb = p0 >> 12, nn0 = p0 & (NPTS-1);

  for(int pi=0; pi<PTS_PER_WAVE; pi++){
    // ---- counted wait. Queue at top: [P(pi)2, (S1 if flush last iter), G(pi)5,
    //      P(pi+1)2] -> vmcnt(2) drains all but P(pi+1). vmcnt(0) only at end. ----
    if(pi == PTS_PER_WAVE-1) asm volatile("s_waitcnt vmcnt(0)" ::: "memory");
    else                     asm volatile("s_waitcnt vmcnt(2)" ::: "memory");

    // ---- flush 4-point batch (points pi-4..pi-1) at pi = 4,8,12 ----
    if(pi >= 4 && (pi & 3) == 0){
      float* op = out + ((size_t)bb*OUTC + lane)*NPTS + nn0 + (pi-4);
      float4 v;
      v.x = ybuf[0*64+lane]; v.y = ybuf[1*64+lane];
      v.z = ybuf[2*64+lane]; v.w = ybuf[3*64+lane];
      *(float4*)op = v;
    }

    // ---- 16 transpose-reads from gbuf + 16 pack reads from pbuf[pi&1] ----
    short4v lo[8], hi[8];
    #pragma unroll
    for(int nt=0; nt<8; nt++){
      asm volatile("ds_read_b64_tr_b16 %0, %1 offset:%2" : "=v"(lo[nt]) : "v"(tra0), "i"(nt*640));
      asm volatile("ds_read_b64_tr_b16 %0, %1 offset:%2" : "=v"(hi[nt]) : "v"(tra1), "i"(nt*640));
    }
    const float* pb = &pbuf_all[w][pi&1][0];
    float p0r[8], p1r[8];
    #pragma unroll
    for(int j=0;j<8;j++){ p0r[j] = pb[koff[j]+l15]; p1r[j] = pb[koff[j]+s2]; }

    asm volatile("s_waitcnt lgkmcnt(0)" ::: "memory");
    __builtin_amdgcn_sched_barrier(0);                 // rule #18: pin consumers after the wait

    // ---- deep prefetch: gather(pi+1) (gbuf consumed), perm(pi+2) (pbuf[pi&1] consumed) ----
    if(pi+1 < PTS_PER_WAVE) STAGE_G(pi+1);
    if(pi+2 < PTS_PER_WAVE) STAGE_P(pi+2);

    // ---- pack perm A-frags (pure VALU on LDS-read values) ----
    short8 a0f, a1f;
    #pragma unroll
    for(int j=0;j<8;j++){
      int kk2 = lg*8 + j;
      a0f[j] = (kk2 < KK) ? (short)f2bf(p0r[j]) : (short)0;
      a1f[j] = (kk2 < KK) ? (short)f2bf(p1r[j]) : (short)0;
    }

    // ---- GEMM1: D[s][c] = sum_k perm[k][s]*gath[k][c]; write .view layout to tbuf ----
    __builtin_amdgcn_s_setprio(1);
    #pragma unroll
    for(int nt=0; nt<8; nt++){
      short8 gf = __builtin_shufflevector(lo[nt], hi[nt], 0,1,2,3,4,5,6,7);
      f32x4 z = {0.f,0.f,0.f,0.f};
      f32x4 c0 = __builtin_amdgcn_mfma_f32_16x16x32_bf16(a0f, gf, z, 0,0,0);
      f32x4 c1 = __builtin_amdgcn_mfma_f32_16x16x32_bf16(a1f, gf, z, 0,0,0);
      const int c = nt*16 + l15;
      {
        int f0 = c*20 + lg*4;                          // s = 4*lg + r
        int byt = (f0*2) ^ (((f0>>7)&7)<<4);
        uint2v pk;
        pk.x = (unsigned)f2bf(c0[0]) | ((unsigned)f2bf(c0[1])<<16);
        pk.y = (unsigned)f2bf(c0[2]) | ((unsigned)f2bf(c0[3])<<16);
        *(uint2v*)((char*)tbuf + byt) = pk;
      }
      if(lg == 0){
        int f0 = c*20 + 16;                            // s = 16 + r
        int byt = (f0*2) ^ (((f0>>7)&7)<<4);
        uint2v pk;
        pk.x = (unsigned)f2bf(c1[0]) | ((unsigned)f2bf(c1[1])<<16);
        pk.y = (unsigned)f2bf(c1[2]) | ((unsigned)f2bf(c1[3])<<16);
        *(uint2v*)((char*)tbuf + byt) = pk;
      }
    }
    __builtin_amdgcn_s_setprio(0);

    // ---- GEMM2: D[kp][o] = sum_c' T[kp][c'] * W[o][c'] — W from LDS, zero VMEM ----
    f32x4 acc[2][4];
    #pragma unroll
    for(int m2=0;m2<2;m2++)
      #pragma unroll
      for(int n2=0;n2<4;n2++){ f32x4 z={0.f,0.f,0.f,0.f}; acc[m2][n2]=z; }

    const int kp1 = (l15 < 4) ? (16 + l15) : 19;       // clamped; dup rows masked in epilogue
    __builtin_amdgcn_s_setprio(1);
    #pragma unroll
    for(int ks=0; ks<4; ks++){
      int a0b = (l15*256 + ks*64 + lg*16) ^ ((l15&7)<<4);
      int a1b = (kp1*256 + ks*64 + lg*16) ^ ((kp1&7)<<4);
      short8 t0 = *(const short8*)((const char*)tbuf + a0b);
      short8 t1 = *(const short8*)((const char*)tbuf + a1b);
      #pragma unroll
      for(int n2=0; n2<4; n2++){
        short8 wf = *(const short8*)((const char*)W_lds + (ks*4+n2)*1024 + lane*16);
        acc[0][n2] = __builtin_amdgcn_mfma_f32_16x16x32_bf16(t0, wf, acc[0][n2], 0,0,0);
        acc[1][n2] = __builtin_amdgcn_mfma_f32_16x16x32_bf16(t1, wf, acc[1][n2], 0,0,0);
      }
    }
    __builtin_amdgcn_s_setprio(0);

    // ---- epilogue: max over kp, buffer y in LDS, BN partials ----
    #pragma unroll
    for(int n2=0; n2<4; n2++){
      float m0 = fmaxf(fmaxf(acc[0][n2][0], acc[0][n2][1]),
                       fmaxf(acc[0][n2][2], acc[0][n2][3]));
      float m1 = fmaxf(fmaxf(acc[1][n2][0], acc[1][n2][1]),
                       fmaxf(acc[1][n2][2], acc[1][n2][3]));
      float mm = fmaxf(m0, (lg == 0) ? m1 : -3.4e38f);
      mm = fmaxf(mm, __shfl_xor(mm, 16));
      mm = fmaxf(mm, __shfl_xor(mm, 32));
      if(lg == 0) ybuf[(pi&3)*64 + n2*16 + l15] = mm;  // conv bias cancels under BN
      bsum[n2] += mm; bsq[n2] += mm*mm;
    }
  }

  // ---- flush last 4-point batch (points 12..15) ----
  {
    float* op = out + ((size_t)bb*OUTC + lane)*NPTS + nn0 + 12;
    float4 v;
    v.x = ybuf[0*64+lane]; v.y = ybuf[1*64+lane];
    v.z = ybuf[2*64+lane]; v.w = ybuf[3*64+lane];
    *(float4*)op = v;
  }

  // ---- block-level stats reduction (red aliases idx storage) ----
  float* red = (float*)&idx_all[0][0];
  __syncthreads();
  if(lg == 0){
    #pragma unroll
    for(int n2=0; n2<4; n2++){
      int o = n2*16 + l15;
      red[w*128 + o]      = bsum[n2];
      red[w*128 + 64 + o] = bsq[n2];
    }
  }
  __syncthreads();
  if(w == 0){
    float s = red[lane] + red[128+lane] + red[256+lane] + red[384+lane];
    atomicAdd(&stats[lane], s);
  } else if(w == 1){
    float s = red[64+lane] + red[192+lane] + red[320+lane] + red[448+lane];
    atomicAdd(&stats[64+lane], s);
  }
}

// fused finalize + apply
__global__ void k_bn2(float* __restrict__ out, const float* __restrict__ stats,
                      const float* __restrict__ gamma, const float* __restrict__ beta){
  __shared__ float ss[128];
  int t = threadIdx.x;
  if(t < 64){
    float inv = 1.f/(float)PTOT;
    float mean = stats[t]*inv;
    float var  = stats[64+t]*inv - mean*mean;
    float rstd = rsqrtf(var + 1e-5f);
    float sc = gamma[t]*rstd;
    ss[t]    = sc;
    ss[64+t] = beta[t] - mean*sc;
  }
  __syncthreads();
  int i = blockIdx.x*256 + t;               // over float4s
  float4 v = ((float4*)out)[i];
  int o = (i >> 10) & 63;
  float sc = ss[o], sh = ss[64+o];
  v.x = v.x*sc + sh; v.y = v.y*sc + sh; v.z = v.z*sc + sh; v.w = v.w*sc + sh;
  ((float4*)out)[i] = v;
}

extern "C" void kernel_launch(void* const* d_in, const int* in_sizes, int n_in,
                              void* d_out, int out_size, void* d_ws, size_t ws_size,
                              hipStream_t stream){
  (void)in_sizes; (void)n_in; (void)ws_size;
  const float* feature    = (const float*)d_in[0];
  const float* permatrix  = (const float*)d_in[1];
  const float* conv_w     = (const float*)d_in[2];
  // d_in[3] = conv_b: cancelled exactly by training-mode BatchNorm
  const float* bn_gamma   = (const float*)d_in[4];
  const float* bn_beta    = (const float*)d_in[5];
  const int*   sp_idx     = (const int*)d_in[6];
  float* out = (float*)d_out;

  unsigned short* flat  = (unsigned short*)d_ws;                         // 8 MB
  float* stats          = (float*)((char*)d_ws + (size_t)8*1024*1024);   // 128 f32
  unsigned short* wpack = (unsigned short*)((char*)d_ws + (size_t)8*1024*1024 + 4096); // 16 KB

  hipMemsetAsync(stats, 0, 128*sizeof(float), stream);

  dim3 gT(NPTS/32, FEATS/32, BATCH), bT(32,8);
  k_transpose<<<gT, bT, 0, stream>>>(feature, flat, conv_w, wpack);

  k_main<<<dim3(PTOT/(WAVES*PTS_PER_WAVE)), dim3(256), 0, stream>>>(
      flat, permatrix, wpack, sp_idx, out, stats);

  k_bn2<<<dim3(out_size/4/256), dim3(256), 0, stream>>>(out, stats, bn_gamma, bn_beta);
}

// Round 17
// 69.468 us; speedup vs baseline: 1.1965x; 1.1097x over previous
//
#include <hip/hip_runtime.h>
#include <hip/hip_bf16.h>

typedef short short8 __attribute__((ext_vector_type(8)));
typedef short short4v __attribute__((ext_vector_type(4)));
typedef float f32x4 __attribute__((ext_vector_type(4)));
typedef unsigned int uint2v __attribute__((ext_vector_type(2)));

#define NPTS 4096
#define BATCH 8
#define PTOT 32768
#define FEATS 128
#define KK 20
#define OUTC 64
#define PTS_PER_WAVE 16
#define WAVES 4

__device__ __forceinline__ unsigned short f2bf(float f){
  union { __hip_bfloat16 h; unsigned short u; } v;
  v.h = __hip_bfloat16(f);
  return v.u;
}

__device__ __forceinline__ void gload_lds16(const void* src, void* dst){
  __builtin_amdgcn_global_load_lds((const __attribute__((address_space(1))) void*)src,
                                   (__attribute__((address_space(3))) void*)dst, 16, 0, 0);
}

// feature [B,128,N] f32 -> flat [B*N, 128] bf16; 32 blocks also pack conv_w
__global__ void k_transpose(const float* __restrict__ f, unsigned short* __restrict__ flat,
                            const float* __restrict__ convw, unsigned short* __restrict__ wp){
  __shared__ float tile[32][33];
  int b = blockIdx.z, c0 = blockIdx.y*32, n0 = blockIdx.x*32;
  int tx = threadIdx.x, ty = threadIdx.y;   // (32,8)
  const float* src = f + ((size_t)b*FEATS + c0)*NPTS + n0;
  #pragma unroll
  for(int i=0;i<4;i++) tile[ty+8*i][tx] = src[(size_t)(ty+8*i)*NPTS + tx];
  // fused wpack: e = (((ks*4+n2)*4+lg)*16+l15)*8+j  (32 blocks x 256 threads)
  if(blockIdx.z == 0 && blockIdx.y == 0 && blockIdx.x < 32){
    int e = blockIdx.x*256 + ty*32 + tx;
    int j = e & 7, l15 = (e>>3)&15, lg = (e>>7)&3, n2 = (e>>9)&3, ks = e>>11;
    int o = n2*16 + l15, c = ks*32 + lg*8 + j;
    wp[e] = f2bf(convw[o*FEATS + c]);
  }
  __syncthreads();
  unsigned short* dst = flat + ((size_t)b*NPTS + n0)*FEATS + c0;
  #pragma unroll
  for(int i=0;i<4;i++) dst[(size_t)(ty+8*i)*FEATS + tx] = f2bf(tile[tx][ty+8*i]);
}

// Laws: relaxed VGPR cap only ((256,4)->64 VGPR->spill, r7). Perm register-
// prefetch across MFMAs spills (r8) -> perm via LDS DMA. pbuf DOUBLE +
// counted vmcnt, never drain 0 in loop (r10/r11). Batched stores + idx in LDS
// (r12). W out of the loop-VMEM queue (r14: 74.6->68). Occupancy pushes all
// lost to per-wave stall cover (r11/r12/r13/r15) -- LDS pins 2 waves/SIMD, so
// VGPR<=256 is free. r17: W fragments 16xshort8 = 64 VGPR, loaded ONCE per
// wave; GEMM2 issues ZERO DS for W (-192cy/pt, DS pipe 56%->40%). (256,2)
// removes spill pressure without occupancy cost. 8-point ybuf flushes merge
// store sectors in L2 (write amp 2x -> 1x).
__global__ __launch_bounds__(256, 2) void k_main(
    const unsigned short* __restrict__ flat,
    const float* __restrict__ perm_g,
    const unsigned short* __restrict__ wpack,
    const int*   __restrict__ idx_g,
    float* __restrict__ out,
    float* __restrict__ stats)
{
  const int t = threadIdx.x, lane = t & 63, w = t >> 6;
  const int l15 = lane & 15, lg = lane >> 4;

  //  gbuf: gather dest [cgrp 0..7][kgrp 0..4][4][16] u16 (DMA, depth-1)
  //  tbuf: GEMM1 output, .view layout XOR-swizzled (split from gbuf so
  //        STAGE_G(pi+1) issues BEFORE GEMM1(pi) -> full GEMM1+GEMM2 cover)
  //  pbuf: perm f32 DOUBLE buffer, DMA'd two iterations ahead
  __shared__ __align__(16) unsigned short gbuf_all[WAVES][2560];     // 20480 B
  __shared__ __align__(16) unsigned short tbuf_all[WAVES][2560];     // 20480 B
  __shared__ __align__(16) float pbuf_all[WAVES][2][400];            // 12800 B
  __shared__ int   idx_all[WAVES][320];                              // 5120 B (red aliases after)
  __shared__ float ybuf_all[WAVES][8*OUTC];                          // 8192 B
  // total 67,072 B -> 2 blocks/CU

  unsigned short* gbuf = gbuf_all[w];
  unsigned short* tbuf = tbuf_all[w];
  int*   idxb = idx_all[w];
  float* ybuf = ybuf_all[w];
  const unsigned gbufb = (unsigned)(size_t)(const __attribute__((address_space(3))) void*)gbuf;

  const int p0 = blockIdx.x*(WAVES*PTS_PER_WAVE) + w*PTS_PER_WAVE;

  // ---- W fragments -> 64 VGPRs, loaded once (coalesced 16B/lane) ----
  short8 wf[16];
  #pragma unroll
  for(int i=0; i<16; i++) wf[i] = *(const short8*)(wpack + i*512 + lane*8);

  // ---- idx prefetch: 320 ints for this wave's 16 points (coalesced) ----
  {
    const int* ib = idx_g + (size_t)p0*KK;
    #pragma unroll
    for(int it=0; it<5; it++) idxb[it*64 + lane] = ib[it*64 + lane];
  }

  // ---- per-lane staging map: chunk q = it*64+lane -> (cgrp,kgrp,krem,chalf) ----
  int krowb4[5], colb[5];
  #pragma unroll
  for(int it=0; it<5; it++){
    int q = it*64 + lane;
    int cg = q/40, r = q - cg*40;
    int kgr = r>>3, rem = r&7, krem = rem>>1, chalf = rem&1;
    krowb4[it] = (kgr*4 + krem)*4;      // idx byte offset for row k
    colb[it]   = cg*32 + chalf*16;      // byte offset within flat row
  }

  // ---- tr-read addresses: cross-lane group-transpose semantics ----
  int kg0 = 2*lg;   if(kg0 > 4) kg0 = 0;
  int kg1 = 2*lg+1; if(kg1 > 4) kg1 = 0;
  const unsigned tra0 = gbufb + kg0*128 + l15*8;
  const unsigned tra1 = gbufb + kg1*128 + l15*8;

  // ---- perm offsets into pbuf (clamped in-bounds; A zeroed for k>=20) ----
  const int s2 = (l15 < 4) ? (16 + l15) : 19;
  int koff[8];
  #pragma unroll
  for(int j=0;j<8;j++){ int kb = lg*160 + j*20; koff[j] = (kb > 380) ? 380 : kb; }

  float bsum[4] = {0,0,0,0}, bsq[4] = {0,0,0,0};

  #define STAGE_G(PI) do{                                                       \
    int pib_ = (PI)*80;                                                         \
    _Pragma("unroll")                                                           \
    for(int it_=0; it_<5; it_++){                                               \
      int id_ = *(const int*)((const char*)idxb + pib_ + krowb4[it_]);          \
      const char* s_ = (const char*)flat + ((size_t)(unsigned)id_*256) + colb[it_]; \
      gload_lds16(s_, (char*)gbuf + it_*1024);                                  \
    } }while(0)

  #define STAGE_P(PI) do{                                                       \
    const char* ps_ = (const char*)(perm_g + (size_t)(p0+(PI))*400);            \
    char* pd_ = (char*)&pbuf_all[w][(PI)&1][0];                                 \
    gload_lds16(ps_ + (size_t)lane*16, pd_);                                    \
    gload_lds16(ps_ + 576 + (size_t)lane*16, pd_ + 576);                        \
  }while(0)

  // prologue in-flight: [wf x16 (drained by first use), G(0) x5, P(0) x2, P(1) x2]
  STAGE_G(0); STAGE_P(0); STAGE_P(1);

  const int bb = p0 >> 12, nn0 = p0 & (NPTS-1);

  for(int pi=0; pi<PTS_PER_WAVE; pi++){
    // ---- counted wait. Queue at top: [P(pi)2, (S2 if pi==9), G(pi)5, P(pi+1)2]
    //      -> vmcnt(2) drains all but P(pi+1). vmcnt(0) only at end. ----
    if(pi == PTS_PER_WAVE-1) asm volatile("s_waitcnt vmcnt(0)" ::: "memory");
    else                     asm volatile("s_waitcnt vmcnt(2)" ::: "memory");

    // ---- flush 8-point batch (points 0..7) at pi=8: 32B/row merges sectors ----
    if(pi == 8){
      float* op = out + ((size_t)bb*OUTC + lane)*NPTS + nn0;
      float4 v0, v1;
      v0.x = ybuf[0*64+lane]; v0.y = ybuf[1*64+lane];
      v0.z = ybuf[2*64+lane]; v0.w = ybuf[3*64+lane];
      v1.x = ybuf[4*64+lane]; v1.y = ybuf[5*64+lane];
      v1.z = ybuf[6*64+lane]; v1.w = ybuf[7*64+lane];
      *(float4*)op     = v0;
      *(float4*)(op+4) = v1;
    }

    // ---- 16 transpose-reads from gbuf + 16 pack reads from pbuf[pi&1] ----
    short4v lo[8], hi[8];
    #pragma unroll
    for(int nt=0; nt<8; nt++){
      asm volatile("ds_read_b64_tr_b16 %0, %1 offset:%2" : "=v"(lo[nt]) : "v"(tra0), "i"(nt*640));
      asm volatile("ds_read_b64_tr_b16 %0, %1 offset:%2" : "=v"(hi[nt]) : "v"(tra1), "i"(nt*640));
    }
    const float* pb = &pbuf_all[w][pi&1][0];
    float p0r[8], p1r[8];
    #pragma unroll
    for(int j=0;j<8;j++){ p0r[j] = pb[koff[j]+l15]; p1r[j] = pb[koff[j]+s2]; }

    asm volatile("s_waitcnt lgkmcnt(0)" ::: "memory");
    __builtin_amdgcn_sched_barrier(0);                 // rule #18: pin consumers after the wait

    // ---- deep prefetch: gather(pi+1) (gbuf consumed), perm(pi+2) (pbuf[pi&1] consumed) ----
    if(pi+1 < PTS_PER_WAVE) STAGE_G(pi+1);
    if(pi+2 < PTS_PER_WAVE) STAGE_P(pi+2);

    // ---- pack perm A-frags (pure VALU on LDS-read values) ----
    short8 a0f, a1f;
    #pragma unroll
    for(int j=0;j<8;j++){
      int kk2 = lg*8 + j;
      a0f[j] = (kk2 < KK) ? (short)f2bf(p0r[j]) : (short)0;
      a1f[j] = (kk2 < KK) ? (short)f2bf(p1r[j]) : (short)0;
    }

    // ---- GEMM1: D[s][c] = sum_k perm[k][s]*gath[k][c]; write .view layout to tbuf ----
    __builtin_amdgcn_s_setprio(1);
    #pragma unroll
    for(int nt=0; nt<8; nt++){
      short8 gf = __builtin_shufflevector(lo[nt], hi[nt], 0,1,2,3,4,5,6,7);
      f32x4 z = {0.f,0.f,0.f,0.f};
      f32x4 c0 = __builtin_amdgcn_mfma_f32_16x16x32_bf16(a0f, gf, z, 0,0,0);
      f32x4 c1 = __builtin_amdgcn_mfma_f32_16x16x32_bf16(a1f, gf, z, 0,0,0);
      const int c = nt*16 + l15;
      {
        int f0 = c*20 + lg*4;                          // s = 4*lg + r
        int byt = (f0*2) ^ (((f0>>7)&7)<<4);
        uint2v pk;
        pk.x = (unsigned)f2bf(c0[0]) | ((unsigned)f2bf(c0[1])<<16);
        pk.y = (unsigned)f2bf(c0[2]) | ((unsigned)f2bf(c0[3])<<16);
        *(uint2v*)((char*)tbuf + byt) = pk;
      }
      if(lg == 0){
        int f0 = c*20 + 16;                            // s = 16 + r
        int byt = (f0*2) ^ (((f0>>7)&7)<<4);
        uint2v pk;
        pk.x = (unsigned)f2bf(c1[0]) | ((unsigned)f2bf(c1[1])<<16);
        pk.y = (unsigned)f2bf(c1[2]) | ((unsigned)f2bf(c1[3])<<16);
        *(uint2v*)((char*)tbuf + byt) = pk;
      }
    }
    __builtin_amdgcn_s_setprio(0);

    // ---- GEMM2: D[kp][o] = sum_c' T[kp][c'] * W[o][c'] — W in REGISTERS ----
    f32x4 acc[2][4];
    #pragma unroll
    for(int m2=0;m2<2;m2++)
      #pragma unroll
      for(int n2=0;n2<4;n2++){ f32x4 z={0.f,0.f,0.f,0.f}; acc[m2][n2]=z; }

    const int kp1 = (l15 < 4) ? (16 + l15) : 19;       // clamped; dup rows masked in epilogue
    __builtin_amdgcn_s_setprio(1);
    #pragma unroll
    for(int ks=0; ks<4; ks++){
      int a0b = (l15*256 + ks*64 + lg*16) ^ ((l15&7)<<4);
      int a1b = (kp1*256 + ks*64 + lg*16) ^ ((kp1&7)<<4);
      short8 t0 = *(const short8*)((const char*)tbuf + a0b);
      short8 t1 = *(const short8*)((const char*)tbuf + a1b);
      #pragma unroll
      for(int n2=0; n2<4; n2++){
        acc[0][n2] = __builtin_amdgcn_mfma_f32_16x16x32_bf16(t0, wf[ks*4+n2], acc[0][n2], 0,0,0);
        acc[1][n2] = __builtin_amdgcn_mfma_f32_16x16x32_bf16(t1, wf[ks*4+n2], acc[1][n2], 0,0,0);
      }
    }
    __builtin_amdgcn_s_setprio(0);

    // ---- epilogue: max over kp, buffer y in LDS, BN partials ----
    #pragma unroll
    for(int n2=0; n2<4; n2++){
      float m0 = fmaxf(fmaxf(acc[0][n2][0], acc[0][n2][1]),
                       fmaxf(acc[0][n2][2], acc[0][n2][3]));
      float m1 = fmaxf(fmaxf(acc[1][n2][0], acc[1][n2][1]),
                       fmaxf(acc[1][n2][2], acc[1][n2][3]));
      float mm = fmaxf(m0, (lg == 0) ? m1 : -3.4e38f);
      mm = fmaxf(mm, __shfl_xor(mm, 16));
      mm = fmaxf(mm, __shfl_xor(mm, 32));
      if(lg == 0) ybuf[(pi&7)*64 + n2*16 + l15] = mm;  // conv bias cancels under BN
      bsum[n2] += mm; bsq[n2] += mm*mm;
    }
  }

  // ---- flush last 8-point batch (points 8..15) ----
  {
    float* op = out + ((size_t)bb*OUTC + lane)*NPTS + nn0 + 8;
    float4 v0, v1;
    v0.x = ybuf[0*64+lane]; v0.y = ybuf[1*64+lane];
    v0.z = ybuf[2*64+lane]; v0.w = ybuf[3*64+lane];
    v1.x = ybuf[4*64+lane]; v1.y = ybuf[5*64+lane];
    v1.z = ybuf[6*64+lane]; v1.w = ybuf[7*64+lane];
    *(float4*)op     = v0;
    *(float4*)(op+4) = v1;
  }

  // ---- block-level stats reduction (red aliases idx storage) ----
  float* red = (float*)&idx_all[0][0];
  __syncthreads();
  if(lg == 0){
    #pragma unroll
    for(int n2=0; n2<4; n2++){
      int o = n2*16 + l15;
      red[w*128 + o]      = bsum[n2];
      red[w*128 + 64 + o] = bsq[n2];
    }
  }
  __syncthreads();
  if(w == 0){
    float s = red[lane] + red[128+lane] + red[256+lane] + red[384+lane];
    atomicAdd(&stats[lane], s);
  } else if(w == 1){
    float s = red[64+lane] + red[192+lane] + red[320+lane] + red[448+lane];
    atomicAdd(&stats[64+lane], s);
  }
}

// fused finalize + apply
__global__ void k_bn2(float* __restrict__ out, const float* __restrict__ stats,
                      const float* __restrict__ gamma, const float* __restrict__ beta){
  __shared__ float ss[128];
  int t = threadIdx.x;
  if(t < 64){
    float inv = 1.f/(float)PTOT;
    float mean = stats[t]*inv;
    float var  = stats[64+t]*inv - mean*mean;
    float rstd = rsqrtf(var + 1e-5f);
    float sc = gamma[t]*rstd;
    ss[t]    = sc;
    ss[64+t] = beta[t] - mean*sc;
  }
  __syncthreads();
  int i = blockIdx.x*256 + t;               // over float4s
  float4 v = ((float4*)out)[i];
  int o = (i >> 10) & 63;
  float sc = ss[o], sh = ss[64+o];
  v.x = v.x*sc + sh; v.y = v.y*sc + sh; v.z = v.z*sc + sh; v.w = v.w*sc + sh;
  ((float4*)out)[i] = v;
}

extern "C" void kernel_launch(void* const* d_in, const int* in_sizes, int n_in,
                              void* d_out, int out_size, void* d_ws, size_t ws_size,
                              hipStream_t stream){
  (void)in_sizes; (void)n_in; (void)ws_size;
  const float* feature    = (const float*)d_in[0];
  const float* permatrix  = (const float*)d_in[1];
  const float* conv_w     = (const float*)d_in[2];
  // d_in[3] = conv_b: cancelled exactly by training-mode BatchNorm
  const float* bn_gamma   = (const float*)d_in[4];
  const float* bn_beta    = (const float*)d_in[5];
  const int*   sp_idx     = (const int*)d_in[6];
  float* out = (float*)d_out;

  unsigned short* flat  = (unsigned short*)d_ws;                         // 8 MB
  float* stats          = (float*)((char*)d_ws + (size_t)8*1024*1024);   // 128 f32
  unsigned short* wpack = (unsigned short*)((char*)d_ws + (size_t)8*1024*1024 + 4096); // 16 KB

  hipMemsetAsync(stats, 0, 128*sizeof(float), stream);

  dim3 gT(NPTS/32, FEATS/32, BATCH), bT(32,8);
  k_transpose<<<gT, bT, 0, stream>>>(feature, flat, conv_w, wpack);

  k_main<<<dim3(PTOT/(WAVES*PTS_PER_WAVE)), dim3(256), 0, stream>>>(
      flat, permatrix, wpack, sp_idx, out, stats);

  k_bn2<<<dim3(out_size/4/256), dim3(256), 0, stream>>>(out, stats, bn_gamma, bn_beta);
}